// Round 10
// baseline (990.874 us; speedup 1.0000x reference)
//
#include <hip/hip_runtime.h>
#include <hip/hip_bf16.h>
#include <cstdint>
#include <cstddef>

#define A_REAL 50000
#define A_PAD  50176      // 196 * 256
#define MT256  196
#define PADROWS 176
#define NBOND  6
#define HD     512
#define FATOM  133
#define FBOND  14
#define KWI    160        // f_atoms block width (133 padded)
#define KU     704        // unified row: nei(512) | bond(32) | f_atoms(160)
#define NMOL   2000
#define MOLPAD 2048
#define APM    25
#define NHID   256

typedef __bf16 bf16x8 __attribute__((ext_vector_type(8)));
typedef float  f32x4  __attribute__((ext_vector_type(4)));
typedef short  short8 __attribute__((ext_vector_type(8)));
typedef short  short4v __attribute__((ext_vector_type(4)));

__device__ __forceinline__ float b2f(unsigned short u) {
  return __uint_as_float(((unsigned int)u) << 16);
}
__device__ __forceinline__ unsigned short f2b(float f) {
  unsigned int x = __float_as_uint(f);
  unsigned int r = (x + 0x7fffu + ((x >> 16) & 1u)) >> 16;
  return (unsigned short)r;
}
// fp16 state (s, h, ff1): 8x finer rounding than bf16, same 2B footprint.
__device__ __forceinline__ unsigned short f2h(float f) {
  _Float16 h = (_Float16)f;                 // v_cvt_f16_f32, RNE
  return *(unsigned short*)&h;
}
__device__ __forceinline__ float h2f(unsigned short u) {
  _Float16 h = *(_Float16*)&u;
  return (float)h;
}

// ---------------- zero pad rows of wU (all allocated slots) + wEnc pad -------
__global__ void zero_pads(unsigned short* __restrict__ wU, unsigned long long sU,
                          int nsAlloc, unsigned short* __restrict__ wEnc)
{
  const int t = blockIdx.x * 256 + threadIdx.x;
  if (t < PADROWS * KU) {
    for (int s = 0; s < nsAlloc; ++s)
      wU[s * sU + (size_t)A_REAL * KU + t] = 0;
  }
  if (t < 48 * 1024) wEnc[(size_t)NMOL * 1024 + t] = 0;
}

// ---------------- f32 weights -> padded bf16 ---------------------------------
// mode 0: plain pad to ldd (Wi [512][133] -> [512][KWI], FFN1 [256][1024]).
// mode 1: Wo [512][645]=[f_atoms|a_msg] -> KU layout:
//         k<512 = a_msg part (src 133+k), 512..543 = 0, 544..676 = f_atoms.
// mode 2: Wh+Wi combined -> KU layout:
//         k<526 = Wh (src k; 512 nei + 14 bond), 526..543 = 0,
//         544..676 = Wi (srcB k-544).
__global__ void convw(unsigned short* __restrict__ dst, const float* __restrict__ src,
                      const float* __restrict__ srcB,
                      int Ksrc, int ldd, int rows, int mode)
{
  const int idx = blockIdx.x * 256 + threadIdx.x;
  if (idx >= rows * ldd) return;
  const int n = idx / ldd, k = idx % ldd;
  float v = 0.f;
  if (mode == 0) {
    if (k < Ksrc) v = src[(size_t)n * Ksrc + k];
  } else if (mode == 1) {
    if (k < 512)                  v = src[(size_t)n * 645 + 133 + k];
    else if (k >= 544 && k < 677) v = src[(size_t)n * 645 + (k - 544)];
  } else {
    if (k < 526)                  v = src[(size_t)n * 526 + k];
    else if (k >= 544 && k < 677) v = srcB[(size_t)n * 133 + (k - 544)];
  }
  dst[(size_t)n * ldd + k] = f2b(v);
}

// ---------------- combined bias bh + bi (f32) --------------------------------
__global__ void bias_comb(float* __restrict__ dst, const float* __restrict__ bh,
                          const float* __restrict__ bi)
{
  const int t = blockIdx.x * 256 + threadIdx.x;
  if (t < HD) dst[t] = bh[t] + bi[t];
}

// ---------------- f_atoms -> wU cols 544..703 (bf16, padded) -----------------
__global__ void atoms_prep(unsigned short* __restrict__ wU, const float* __restrict__ f_atoms)
{
  const int idx = blockIdx.x * 256 + threadIdx.x;
  if (idx >= A_PAD * KWI) return;
  const int r = idx / KWI, c = idx % KWI;
  float v = 0.f;
  if (r < A_REAL && c < FATOM) v = f_atoms[(size_t)r * FATOM + c];
  wU[(size_t)r * KU + 544 + c] = f2b(v);
}

// ---------------- bond gather-sum -> wU cols 512..543 (once per side) --------
__global__ void bond_gather(unsigned short* __restrict__ wU, const float* __restrict__ f_bonds,
                            const int* __restrict__ a2b)
{
  const int a = blockIdx.x * 256 + threadIdx.x;
  if (a >= A_REAL) return;
  float acc[FBOND];
  #pragma unroll
  for (int c = 0; c < FBOND; ++c) acc[c] = 0.f;
  #pragma unroll
  for (int j = 0; j < NBOND; ++j) {
    const int b = a2b[a * NBOND + j];
    const float* row = f_bonds + (size_t)b * FBOND;
    #pragma unroll
    for (int c = 0; c < FBOND; ++c) acc[c] += row[c];
  }
  unsigned short* d = wU + (size_t)a * KU + 512;
  #pragma unroll
  for (int c = 0; c < FBOND; ++c) d[c] = f2b(acc[c]);
  #pragma unroll
  for (int c = FBOND; c < 32; ++c) d[c] = 0;
}

// ------- 6-neighbor gather-sum of relu(fp16 state) -> wU cols 0..511 ---------
__launch_bounds__(256)
__global__ void gather6(unsigned short* __restrict__ dst, unsigned long long sDst,
                        const unsigned short* __restrict__ st, unsigned long long sSt,
                        const int* __restrict__ a2aA, const int* __restrict__ a2aB,
                        int bps)
{
  const int blk  = blockIdx.x;
  const int side = blk / bps;
  const int lb   = blk - side * bps;
  const int* a2a = side ? a2aB : a2aA;
  unsigned short* d = dst + side * sDst;
  const unsigned short* state = st + side * sSt;

  const int a    = lb * 4 + (threadIdx.x >> 6);
  const int lane = threadIdx.x & 63;
  const int* idx = a2a + a * NBOND;
  float acc[8] = {0.f,0.f,0.f,0.f,0.f,0.f,0.f,0.f};
  #pragma unroll
  for (int j = 0; j < NBOND; ++j) {
    const int r = idx[j];
    short8 v = *reinterpret_cast<const short8*>(state + (size_t)r * HD + lane * 8);
    #pragma unroll
    for (int e = 0; e < 8; ++e) acc[e] += fmaxf(h2f((unsigned short)v[e]), 0.f);
  }
  short8 o;
  #pragma unroll
  for (int e = 0; e < 8; ++e) o[e] = (short)f2b(acc[e]);
  *reinterpret_cast<short8*>(d + (size_t)a * KU + lane * 8) = o;
}

// ---------------- bf16 MFMA GEMM, 256x128 tile, depth-2 prefetch, dual-side --
// C[M x N] = A[M x K] * W[N x K]^T  (bf16 in, fp32 accum, fp16 out)
// 8 waves/512thr, LDS ring 3x24KB, counted vmcnt(3); stage(t+2) mid-compute.
// T2 LDS SWIZZLE (r10): the old linear layout read bank quad
// (16*row+4*chunk)%32 -> only 2 values over 16 lanes = 8-way conflict
// (8.8M conflict cycles/dispatch measured r9). Per rule #21 LDS stays
// LINEAR (global_load_lds dest is wave-uniform+lane*16); instead the
// GLOBAL source chunk is pre-swizzled: chunk' = chunk ^ ((row>>1)&3),
// and fragment reads XOR the same term -> 8 distinct quads = 2-way (free).
// Bit-identical numerics (pure lane permutation within 64B segments).
// x-FOLD: Wi folded into Wh (K=704, bias bh+bi); state/h/ff1 stored FP16.
// OPERAND-SWAPPED MFMA: lane = M-row, 4 acc regs = 4 consecutive N cols.
// MODE 0: out = fp16(acc + bias)         (pre-relu state; relu in gather)
// MODE 2: out = fp16(relu(acc + bias))   (Wo / FFN1)
struct GemmP {
  const unsigned short* A; unsigned long long sA; int lda;
  const unsigned short* W; unsigned long long sW; int ldb;
  const float* bias0; const float* bias1;
  unsigned short* outA; unsigned long long sOutA;
  int outLd; int K; int bps;
};

template<int MODE, int NTN>
__launch_bounds__(512, 4)
__global__ void gemm_bf16(GemmP p)
{
  __shared__ alignas(16) unsigned short lA[3][256 * 32];
  __shared__ alignas(16) unsigned short lB[3][128 * 32];
  const int tid  = threadIdx.x;
  const int lane = tid & 63;
  const int wav  = tid >> 6;
  const int wm = wav >> 1, wn = wav & 1;

  // bijective chunked XCD swizzle (m204)
  const int nwg = gridDim.x;
  const int id  = blockIdx.x;
  const int q = nwg >> 3, r = nwg & 7;
  const int xcd = id & 7, jj = id >> 3;
  const int gid = (xcd < r ? xcd * (q + 1) : r * (q + 1) + (xcd - r) * q) + jj;
  const int side = gid / p.bps;
  const int lid  = gid - side * p.bps;
  const int bxt = lid / NTN;
  const int byt = lid - bxt * NTN;
  const size_t tileM = (size_t)bxt * 256;
  const int n0 = byt * 128;

  const float* bias = side ? p.bias1 : p.bias0;
  const unsigned short* Aside = p.A + side * p.sA;
  const unsigned short* Wside = p.W + side * p.sW;
  unsigned short* outA = p.outA + side * p.sOutA;

  const int srow = tid >> 2;                          // staging row within pass
  const int sgcol = (((tid & 3) ^ ((tid >> 3) & 3)) * 8);  // swizzled global chunk
  const int fr = lane & 15;
  const int xr = ((lane & 15) >> 1) & 3;              // read-side XOR term
  const int fks = (((lane >> 4) ^ xr) * 8);           // swizzled read slot

  f32x4 acc[4][4];
  #pragma unroll
  for (int m = 0; m < 4; ++m)
    #pragma unroll
    for (int n = 0; n < 4; ++n)
      acc[m][n] = (f32x4){0.f, 0.f, 0.f, 0.f};

  const unsigned short* Abase = Aside + tileM * (size_t)p.lda;
  const unsigned short* Wbase = Wside + (size_t)n0 * (size_t)p.ldb;
  const int lda = p.lda, ldb = p.ldb;
  const int nt = p.K >> 5;

  auto stage = [&](int t, int buf) {
    const int k0 = t * 32;
    #pragma unroll
    for (int i = 0; i < 2; ++i) {
      const int rr = i * 128 + srow;
      const unsigned short* ga = Abase + (size_t)rr * lda + (k0 + sgcol);
      __builtin_amdgcn_global_load_lds(
          (const __attribute__((address_space(1))) unsigned int*)ga,
          (__attribute__((address_space(3))) unsigned int*)&lA[buf][rr * 32 + (tid & 3) * 8], 16, 0, 0);
    }
    const unsigned short* gb = Wbase + (size_t)srow * ldb + (k0 + sgcol);
    __builtin_amdgcn_global_load_lds(
        (const __attribute__((address_space(1))) unsigned int*)gb,
        (__attribute__((address_space(3))) unsigned int*)&lB[buf][srow * 32 + (tid & 3) * 8], 16, 0, 0);
  };

  stage(0, 0);
  if (nt > 1) stage(1, 1);

  int buf = 0;
  for (int t = 0; t < nt; ++t) {
    if (t + 1 < nt) asm volatile("s_waitcnt vmcnt(3)" ::: "memory");
    else            asm volatile("s_waitcnt vmcnt(0)" ::: "memory");
    __builtin_amdgcn_s_barrier();
    asm volatile("" ::: "memory");

    bf16x8 af[4], bfm[4];
    #pragma unroll
    for (int m = 0; m < 4; ++m)
      af[m] = *reinterpret_cast<const bf16x8*>(&lA[buf][(wm * 64 + m * 16 + fr) * 32 + fks]);
    #pragma unroll
    for (int n = 0; n < 4; ++n)
      bfm[n] = *reinterpret_cast<const bf16x8*>(&lB[buf][(wn * 64 + n * 16 + fr) * 32 + fks]);

    if (t + 2 < nt) {
      int b2v = buf + 2; if (b2v >= 3) b2v -= 3;
      stage(t + 2, b2v);
    }

    // operand-swapped: acc[m][n] reg i, lane l =
    //   C[tileM + wm*64 + m*16 + (l&15)][n0 + wn*64 + n*16 + (l>>4)*4 + i]
    #pragma unroll
    for (int m = 0; m < 4; ++m)
      #pragma unroll
      for (int n = 0; n < 4; ++n)
        acc[m][n] = __builtin_amdgcn_mfma_f32_16x16x32_bf16(bfm[n], af[m], acc[m][n], 0, 0, 0);

    buf = (buf == 2) ? 0 : buf + 1;
  }

  const int erow = lane & 15;
  const int ecol = (lane >> 4) * 4;
  #pragma unroll
  for (int m = 0; m < 4; ++m) {
    const size_t rowg = tileM + wm * 64 + m * 16 + erow;
    #pragma unroll
    for (int n = 0; n < 4; ++n) {
      const int colg = n0 + wn * 64 + n * 16 + ecol;
      const f32x4 bv = *reinterpret_cast<const f32x4*>(&bias[colg]);
      const size_t off = rowg * (size_t)p.outLd + colg;
      float v[4];
      #pragma unroll
      for (int e = 0; e < 4; ++e) v[e] = acc[m][n][e] + bv[e];
      short4v o;
      if (MODE == 0) {
        #pragma unroll
        for (int e = 0; e < 4; ++e) o[e] = (short)f2h(v[e]);
      } else {
        #pragma unroll
        for (int e = 0; e < 4; ++e) o[e] = (short)f2h(fmaxf(v[e], 0.f));
      }
      *reinterpret_cast<short4v*>(&outA[off]) = o;
    }
  }
}

// ---------------- per-molecule mean over 25 atoms -> enc (bf16), dual-side ---
__launch_bounds__(256)
__global__ void readout(const unsigned short* __restrict__ h, unsigned long long sH,
                        unsigned short* __restrict__ enc, int sideBase, int bps)
{
  const int blk = blockIdx.x;
  const int s   = blk / bps;
  const int mol = blk - s * bps;
  const int t = threadIdx.x;
  const unsigned short* base = h + s * sH + (size_t)mol * APM * HD + t * 2;
  float s0 = 0.f, s1 = 0.f;
  #pragma unroll
  for (int r = 0; r < APM; ++r) {
    unsigned int v = *reinterpret_cast<const unsigned int*>(base + (size_t)r * HD);
    s0 += h2f((unsigned short)(v & 0xffffu));
    s1 += h2f((unsigned short)(v >> 16));
  }
  s0 *= (1.f / 25.f);
  s1 *= (1.f / 25.f);
  unsigned int o = (unsigned int)f2b(s0) | ((unsigned int)f2b(s1) << 16);
  const int colOff = (sideBase + s) * HD;
  *reinterpret_cast<unsigned int*>(enc + (size_t)mol * 1024 + colOff + t * 2) = o;
}

// ---------------- final dot with ffn2 (ff1 is fp16) --------------------------
__launch_bounds__(256)
__global__ void ffn2_red(const unsigned short* __restrict__ ff1, const float* __restrict__ w2,
                         const float* __restrict__ b2, float* __restrict__ out)
{
  __shared__ float red[256];
  const int mol = blockIdx.x, t = threadIdx.x;
  red[t] = h2f(ff1[(size_t)mol * NHID + t]) * w2[t];
  __syncthreads();
  #pragma unroll
  for (int s = 128; s > 0; s >>= 1) {
    if (t < s) red[t] += red[t + s];
    __syncthreads();
  }
  if (t == 0) out[mol] = red[0] + b2[0];
}

// -----------------------------------------------------------------------------
extern "C" void kernel_launch(void* const* d_in, const int* in_sizes, int n_in,
                              void* d_out, int out_size, void* d_ws, size_t ws_size,
                              hipStream_t stream)
{
  (void)in_sizes; (void)n_in; (void)out_size;

  // NS=2 (both sides in one pipeline) needs ~253.05 MB after the x-fold.
  const int NS = (ws_size >= 253100000ull) ? 2 : 1;

  unsigned char* p = (unsigned char*)d_ws;
  auto take = [&](size_t bytes) -> unsigned short* {
    unsigned short* r = (unsigned short*)p;
    p += (bytes + 1023) & ~(size_t)1023;
    return r;
  };
  const unsigned long long sX = (unsigned long long)A_PAD * HD;   // elems
  const unsigned long long sU = (unsigned long long)A_PAD * KU;
  unsigned short* wS   = take((size_t)NS * sX * 2);   // fp16 state s / h
  unsigned short* wU   = take((size_t)NS * sU * 2);   // bf16 [nei|bond|f_atoms]
  unsigned short* wEnc = take((size_t)MOLPAD * 1024 * 2);   // bf16
  unsigned short* wFF1 = take((size_t)MOLPAD * NHID * 2);   // fp16
  unsigned short* wWiB = take((size_t)NS * 512 * KWI * 2);
  unsigned short* wWhC = take((size_t)NS * 512 * KU * 2);   // [Wh|0|Wi]
  unsigned short* wWoB = take((size_t)NS * 512 * KU * 2);
  unsigned short* wF1B = take((size_t)NHID * 1024 * 2);
  float*          wBC  = (float*)take((size_t)NS * HD * 4); // bh+bi

  const float* biasWi[2]; const float* biasWo[2];
  const int* a2aP[2];
  for (int s = 0; s < 2; ++s) {
    biasWi[s] = (const float*)d_in[s * 10 + 5];
    biasWo[s] = (const float*)d_in[s * 10 + 9];
    a2aP[s]   = (const int*)  d_in[s * 10 + 2];
  }

  zero_pads<<<484, 256, 0, stream>>>(wU, sU, NS, wEnc);

  auto prep = [&](int side, int slot) {
    const float* f_atoms = (const float*)d_in[side * 10 + 0];
    const float* f_bonds = (const float*)d_in[side * 10 + 1];
    const int*   a2b     = (const int*)  d_in[side * 10 + 3];
    const float* Wi_w    = (const float*)d_in[side * 10 + 4];
    const float* Wi_b    = (const float*)d_in[side * 10 + 5];
    const float* Wh_w    = (const float*)d_in[side * 10 + 6];
    const float* Wh_b    = (const float*)d_in[side * 10 + 7];
    const float* Wo_w    = (const float*)d_in[side * 10 + 8];
    convw<<<(512 * KWI) / 256, 256, 0, stream>>>(wWiB + slot * 512 * KWI, Wi_w, nullptr,
                                                 FATOM, KWI, 512, 0);
    convw<<<(512 * KU) / 256, 256, 0, stream>>>(wWhC + slot * 512 * KU, Wh_w, Wi_w,
                                                526, KU, 512, 2);
    convw<<<(512 * KU) / 256, 256, 0, stream>>>(wWoB + slot * 512 * KU, Wo_w, nullptr,
                                                645, KU, 512, 1);
    bias_comb<<<2, 256, 0, stream>>>(wBC + slot * HD, Wh_b, Wi_b);
    atoms_prep<<<(A_PAD * KWI) / 256, 256, 0, stream>>>(wU + slot * sU, f_atoms);
    bond_gather<<<(A_REAL + 255) / 256, 256, 0, stream>>>(wU + slot * sU, f_bonds, a2b);
  };

  auto mp = [&](int sb, int ns) {
    const int BPS = MT256 * 4;           // 784 blocks per side
    GemmP g;
    // s0 = f_atoms @ Wi^T + bi   (A = wU cols 544.., K=160)
    g = { wU + 544, sU, KU, wWiB, 512ull * KWI, KWI,
          biasWi[sb], biasWi[sb + ns - 1], wS, sX, HD, KWI, BPS };
    gemm_bf16<0, 4><<<ns * BPS, 512, 0, stream>>>(g);
    for (int it = 0; it < 3; ++it) {
      gather6<<<ns * (A_REAL / 4), 256, 0, stream>>>(
          wU, sU, wS, sX, a2aP[sb], a2aP[sb + ns - 1], A_REAL / 4);
      // s = [nei|bond|f_atoms] @ [Wh|0|Wi]^T + (bh+bi)   (x-fold, K=704)
      g = { wU, sU, KU, wWhC, 512ull * KU, KU,
            wBC, wBC + (ns - 1) * HD, wS, sX, HD, KU, BPS };
      gemm_bf16<0, 4><<<ns * BPS, 512, 0, stream>>>(g);
    }
    gather6<<<ns * (A_REAL / 4), 256, 0, stream>>>(
        wU, sU, wS, sX, a2aP[sb], a2aP[sb + ns - 1], A_REAL / 4);
    // h = relu([nei|bond|f_atoms] @ Wo'^T + bo) -> wS (state dead)
    g = { wU, sU, KU, wWoB, 512ull * KU, KU,
          biasWo[sb], biasWo[sb + ns - 1], wS, sX, HD, KU, BPS };
    gemm_bf16<2, 4><<<ns * BPS, 512, 0, stream>>>(g);
    readout<<<ns * NMOL, 256, 0, stream>>>(wS, sX, wEnc, sb, NMOL);
  };

  if (NS == 2) {
    prep(0, 0); prep(1, 1);
    mp(0, 2);
  } else {
    prep(0, 0); mp(0, 1);
    prep(1, 0); mp(1, 1);
  }

  const float* ffn1_w = (const float*)d_in[20];
  const float* ffn1_b = (const float*)d_in[21];
  const float* ffn2_w = (const float*)d_in[22];
  const float* ffn2_b = (const float*)d_in[23];

  convw<<<(NHID * 1024) / 256, 256, 0, stream>>>(wF1B, ffn1_w, nullptr, 1024, 1024, NHID, 0);
  GemmP gf = { wEnc, 0, 1024, wF1B, 0, 1024,
               ffn1_b, ffn1_b, wFF1, 0, NHID, 1024, 16 };
  gemm_bf16<2, 2><<<16, 512, 0, stream>>>(gf);
  ffn2_red<<<NMOL, 256, 0, stream>>>(wFF1, ffn2_w, ffn2_b, (float*)d_out);
}